// Round 3
// baseline (366.493 us; speedup 1.0000x reference)
//
#include <hip/hip_runtime.h>

#define BINS 10
#define NTHREADS 256
#define COLS 128   // private histogram columns; col = tid & 127

// ---------------------------------------------------------------------------
// GHM loss, single fused pass.
//   out = (1/tot) * sum_b bin_w[b] * bceSum[b]
// R3:
//  - algebraic core: for t in {0,1},  y = t ? x : -x,  q = sigmoid(y),
//    g = |sigmoid(x)-t| = 1-q,  bce = -ln(q).   (11 VALU + 3 trans / elem)
//  - binning via fire-and-forget LDS float atomics (ds_add_f32 no-return):
//    s[bin][tid&127] -> no RMW latency chain (R2's mistake), no intra-wave
//    same-address collisions, bank = col mod 32 -> 2-way aliasing (free).
//  - LDS ~10.5 KB -> 8 blocks/CU, 100% occupancy, grid 2048 exact.
// ---------------------------------------------------------------------------

__device__ __forceinline__ float wave_reduce_add(float v) {
#pragma unroll
    for (int off = 32; off > 0; off >>= 1) v += __shfl_down(v, off, 64);
    return v;
}

__global__ __launch_bounds__(NTHREADS) void ghm_pass1(
    const float* __restrict__ pred, const int* __restrict__ target,
    float* __restrict__ g_sum,          // [BINS] bce sums
    unsigned int* __restrict__ g_cnt,   // [BINS] counts
    int n4, int n)
{
    __shared__ float s_cnt[BINS][COLS];
    __shared__ float s_sum[BINS][COLS];
    __shared__ float r_sum[BINS];
    __shared__ float r_cnt[BINS];

    const int tid = threadIdx.x;
    const int col = tid & (COLS - 1);

    for (int i = tid; i < BINS * COLS; i += NTHREADS) {
        (&s_cnt[0][0])[i] = 0.f;
        (&s_sum[0][0])[i] = 0.f;
    }
    if (tid < BINS) { r_sum[tid] = 0.f; r_cnt[tid] = 0.f; }
    __syncthreads();

    const float4* __restrict__ p4 = reinterpret_cast<const float4*>(pred);
    const int4*   __restrict__ t4 = reinterpret_cast<const int4*>(target);

    const int gtid   = blockIdx.x * blockDim.x + tid;
    const int stride = gridDim.x * blockDim.x;

    for (int i = gtid; i < n4; i += stride) {
        const float4 xv = p4[i];
        const int4   tv = t4[i];
        const float xs[4] = {xv.x, xv.y, xv.z, xv.w};
        const int   ts[4] = {tv.x, tv.y, tv.z, tv.w};
#pragma unroll
        for (int j = 0; j < 4; ++j) {
            const float x = xs[j];
            const int   t = ts[j];           // in {0,1}
            // y = t ? x : -x   (sign flip when t==0)
            const float y = __int_as_float(__float_as_int(x) ^ ((t ^ 1) << 31));
            const float E   = __expf(-y);            // exp(-y), |y|<~6 -> safe
            const float q   = __builtin_amdgcn_rcpf(1.0f + E);  // sigmoid(y)
            const float g   = 1.0f - q;              // |sigmoid(x) - t|
            const float bce = -__logf(q);            // stable BCE, exact identity
            int k = (int)(g * 10.0f);                // == searchsorted-right - 1
            k = (k > BINS - 1) ? (BINS - 1) : k;
            atomicAdd(&s_cnt[k][col], 1.0f);         // ds_add_f32, no-return
            atomicAdd(&s_sum[k][col], bce);
        }
    }

    // Scalar tail (N % 4); N=2^25 -> empty.
    if (gtid == 0) {
        for (int i = n4 * 4; i < n; ++i) {
            const float x = pred[i];
            const int   t = target[i];
            const float y = __int_as_float(__float_as_int(x) ^ ((t ^ 1) << 31));
            const float E   = __expf(-y);
            const float q   = __builtin_amdgcn_rcpf(1.0f + E);
            const float g   = 1.0f - q;
            const float bce = -__logf(q);
            int k = (int)(g * 10.0f);
            k = (k > BINS - 1) ? (BINS - 1) : k;
            atomicAdd(&s_cnt[k][col], 1.0f);
            atomicAdd(&s_sum[k][col], bce);
        }
    }
    __syncthreads();

    // Threads 0..127 (waves 0,1 fully active) reduce the private columns.
    if (tid < COLS) {
        const int lane = tid & 63;
#pragma unroll
        for (int b = 0; b < BINS; ++b) {
            const float v = wave_reduce_add(s_sum[b][tid]);
            const float c = wave_reduce_add(s_cnt[b][tid]);
            if (lane == 0) { atomicAdd(&r_sum[b], v); atomicAdd(&r_cnt[b], c); }
        }
    }
    __syncthreads();

    if (tid < BINS) {
        atomicAdd(&g_sum[tid], r_sum[tid]);
        // block partial count fits exactly in f32 (<= 2^24)
        atomicAdd(&g_cnt[tid], (unsigned int)(r_cnt[tid] + 0.5f));
    }
}

__global__ void ghm_finalize(const float* __restrict__ g_sum,
                             const unsigned int* __restrict__ g_cnt,
                             const float* __restrict__ acc_sum,
                             float* __restrict__ out, float tot)
{
    if (threadIdx.x == 0 && blockIdx.x == 0) {
        float binw[BINS];
        int n = 0;
#pragma unroll
        for (int b = 0; b < BINS; ++b) {
            const float c  = (float)g_cnt[b];
            const bool  ne = (c > 0.0f);
            const float accn = ne ? (0.9f * acc_sum[b] + 0.1f * c) : acc_sum[b];
            binw[b] = ne ? (tot / accn) : 0.0f;
            n += ne ? 1 : 0;
        }
        const float scale = (n > 0) ? (1.0f / (float)n) : 1.0f;
        float res = 0.0f;
#pragma unroll
        for (int b = 0; b < BINS; ++b) res += (binw[b] * scale) * g_sum[b];
        out[0] = res / tot;
    }
}

extern "C" void kernel_launch(void* const* d_in, const int* in_sizes, int n_in,
                              void* d_out, int out_size, void* d_ws, size_t ws_size,
                              hipStream_t stream) {
    const float* pred    = (const float*)d_in[0];
    const int*   target  = (const int*)d_in[1];
    const float* acc_sum = (const float*)d_in[2];
    float*       out     = (float*)d_out;

    const int n  = in_sizes[0];
    const int n4 = n / 4;

    float*        g_sum = (float*)d_ws;
    unsigned int* g_cnt = (unsigned int*)((float*)d_ws + BINS);

    // Accumulators must be zeroed every call (ws poisoned once, not re-poisoned).
    hipMemsetAsync(d_ws, 0, 2 * BINS * sizeof(float), stream);

    ghm_pass1<<<2048, NTHREADS, 0, stream>>>(pred, target, g_sum, g_cnt, n4, n);

    const float tot = (float)(n > 1 ? n : 1);
    ghm_finalize<<<1, 64, 0, stream>>>(g_sum, g_cnt, acc_sum, out, tot);
}

// Round 4
// 91.766 us; speedup vs baseline: 3.9938x; 3.9938x over previous
//
#include <hip/hip_runtime.h>

#define BINS 10
#define NTHREADS 256

// ---------------------------------------------------------------------------
// GHM loss, single fused pass. R4: staircase accumulation, register-only.
//   y = t ? x : -x ;  bce = ln(1+exp(-y))  (no rcp, no g)
//   bin predicate:  g >= b/10  <=>  y <= c_b,  c_b = ln((10-b)/b)
//   cumulative sums T_b (per-lane VGPR), cumulative counts C_b via
//   __ballot+popcount -> scalar pipe (s_bcnt1_b64 + s_add, ~free).
//   Finalize: S_b = T_b - T_{b+1}, cnt_b = C_b - C_{b+1}, then GHM math.
// R3 lesson: per-element LDS atomics (ds_add_f32) cost ~200 cyc effective;
// keep everything in registers until the epilogue.
// ---------------------------------------------------------------------------

__device__ __forceinline__ float wave_reduce_add(float v) {
#pragma unroll
    for (int off = 32; off > 0; off >>= 1) v += __shfl_down(v, off, 64);
    return v;
}

__global__ __launch_bounds__(NTHREADS) void ghm_pass1(
    const float* __restrict__ pred, const int* __restrict__ target,
    float* __restrict__ g_T,            // [BINS] cumulative bce sums
    unsigned int* __restrict__ g_C,     // [BINS] cumulative counts
    int n4, int n)
{
    // c_b = ln((10-b)/b), b=1..9 (index 0 unused)
    const float C[BINS] = {0.f,
        2.19722458f, 1.38629436f, 0.84729786f, 0.40546511f, 0.0f,
        -0.40546511f, -0.84729786f, -1.38629436f, -2.19722458f};

    float T[BINS];
    unsigned int cnt[BINS];   // wave-uniform (ballot-derived) -> SGPRs
#pragma unroll
    for (int b = 0; b < BINS; ++b) { T[b] = 0.f; cnt[b] = 0u; }

    const float4* __restrict__ p4 = reinterpret_cast<const float4*>(pred);
    const int4*   __restrict__ t4 = reinterpret_cast<const int4*>(target);

    const int tid    = threadIdx.x;
    const int gtid   = blockIdx.x * blockDim.x + tid;
    const int stride = gridDim.x * blockDim.x;

    for (int i = gtid; i < n4; i += stride) {
        const float4 xv = p4[i];
        const int4   tv = t4[i];
        const float xs[4] = {xv.x, xv.y, xv.z, xv.w};
        const int   ts[4] = {tv.x, tv.y, tv.z, tv.w};
        // elements processed this round (all lanes in lockstep here)
        cnt[0] += (unsigned int)(4 * __popcll(__ballot(1)));
#pragma unroll
        for (int j = 0; j < 4; ++j) {
            const float x = xs[j];
            const float y = (ts[j] != 0) ? x : -x;
            const float E = __expf(-y);        // exp2(-y*log2e)
            const float bce = __logf(1.0f + E);
            T[0] += bce;
#pragma unroll
            for (int b = 1; b < BINS; ++b) {
                const bool p = (y <= C[b]);
                T[b] += p ? bce : 0.0f;                       // v_cmp+cndmask+add
                cnt[b] += (unsigned int)__popcll(__ballot(p)); // SALU bcnt+add
            }
        }
    }

    // Scalar tail (n % 4); N=2^25 -> empty. Ballot inside divergence counts
    // only active lanes, so the SALU counts stay correct.
    if (gtid == 0) {
        for (int i = n4 * 4; i < n; ++i) {
            const float x = pred[i];
            const float y = (target[i] != 0) ? x : -x;
            const float E = __expf(-y);
            const float bce = __logf(1.0f + E);
            T[0] += bce;
            cnt[0] += (unsigned int)__popcll(__ballot(1));
#pragma unroll
            for (int b = 1; b < BINS; ++b) {
                const bool p = (y <= C[b]);
                T[b] += p ? bce : 0.0f;
                cnt[b] += (unsigned int)__popcll(__ballot(p));
            }
        }
    }

    // wave reduce (sums) -> block combine in LDS -> one global atomic per bin
    __shared__ float        r_T[BINS];
    __shared__ unsigned int r_C[BINS];
    if (tid < BINS) { r_T[tid] = 0.f; r_C[tid] = 0u; }
    __syncthreads();

    const int lane = tid & 63;
#pragma unroll
    for (int b = 0; b < BINS; ++b) {
        const float v = wave_reduce_add(T[b]);
        if (lane == 0) {
            atomicAdd(&r_T[b], v);       // 10 LDS atomics per wave: negligible
            atomicAdd(&r_C[b], cnt[b]);  // cnt already wave-reduced (ballot)
        }
    }
    __syncthreads();

    if (tid < BINS) {
        atomicAdd(&g_T[tid], r_T[tid]);
        atomicAdd(&g_C[tid], r_C[tid]);
    }
}

__global__ void ghm_finalize(const float* __restrict__ g_T,
                             const unsigned int* __restrict__ g_C,
                             const float* __restrict__ acc_sum,
                             float* __restrict__ out, float tot)
{
    if (threadIdx.x == 0 && blockIdx.x == 0) {
        float S[BINS];
        float cntf[BINS];
#pragma unroll
        for (int b = 0; b < BINS; ++b) {
            const float Tn = (b + 1 < BINS) ? g_T[b + 1] : 0.f;
            const unsigned int Cn = (b + 1 < BINS) ? g_C[b + 1] : 0u;
            S[b]    = g_T[b] - Tn;
            cntf[b] = (float)(g_C[b] - Cn);
        }
        float binw[BINS];
        int nne = 0;
#pragma unroll
        for (int b = 0; b < BINS; ++b) {
            const bool ne = (cntf[b] > 0.0f);
            const float accn = ne ? (0.9f * acc_sum[b] + 0.1f * cntf[b]) : acc_sum[b];
            binw[b] = ne ? (tot / accn) : 0.0f;
            nne += ne ? 1 : 0;
        }
        const float scale = (nne > 0) ? (1.0f / (float)nne) : 1.0f;
        float res = 0.0f;
#pragma unroll
        for (int b = 0; b < BINS; ++b) res += (binw[b] * scale) * S[b];
        out[0] = res / tot;
    }
}

extern "C" void kernel_launch(void* const* d_in, const int* in_sizes, int n_in,
                              void* d_out, int out_size, void* d_ws, size_t ws_size,
                              hipStream_t stream) {
    const float* pred    = (const float*)d_in[0];
    const int*   target  = (const int*)d_in[1];
    const float* acc_sum = (const float*)d_in[2];
    float*       out     = (float*)d_out;

    const int n  = in_sizes[0];
    const int n4 = n / 4;

    float*        g_T = (float*)d_ws;
    unsigned int* g_C = (unsigned int*)((float*)d_ws + BINS);

    // Zero accumulators every call (ws poisoned once, not re-poisoned).
    hipMemsetAsync(d_ws, 0, 2 * BINS * sizeof(float), stream);

    ghm_pass1<<<2048, NTHREADS, 0, stream>>>(pred, target, g_T, g_C, n4, n);

    const float tot = (float)(n > 1 ? n : 1);
    ghm_finalize<<<1, 64, 0, stream>>>(g_T, g_C, acc_sum, out, tot);
}

// Round 5
// 88.550 us; speedup vs baseline: 4.1388x; 1.0363x over previous
//
#include <hip/hip_runtime.h>

#define BINS 10
#define NTHREADS 256

// ---------------------------------------------------------------------------
// GHM loss, single fused pass. R5: register staircase + manual 2-deep
// software pipeline (prefetch next 2xfloat4/2xint4 while computing current).
//   y = t ? x : -x ;  E = exp2(-y*log2e) ;  bce2 = log2(1+E)  [*ln2 deferred]
//   bin predicate: g >= b/10  <=>  y <= c_b = ln((10-b)/b)
//   cumulative sums T2[b] (f32 VGPR) + cumulative counts cnt[b] (u32,
//   v_cmp+v_addc sharing the sum's compare). No LDS / no SALU in main loop.
// R3 lesson: no per-element LDS ops. R4 lesson: no ballot->scalar-pipe chain.
// ---------------------------------------------------------------------------

__device__ __forceinline__ float wave_reduce_add(float v) {
#pragma unroll
    for (int off = 32; off > 0; off >>= 1) v += __shfl_down(v, off, 64);
    return v;
}
__device__ __forceinline__ unsigned int wave_reduce_addu(unsigned int v) {
#pragma unroll
    for (int off = 32; off > 0; off >>= 1) v += __shfl_down((int)v, off, 64);
    return v;
}

// c_b = ln((10-b)/b), b=1..9
#define GHM_C1  2.19722458f
#define GHM_C2  1.38629436f
#define GHM_C3  0.84729786f
#define GHM_C4  0.40546511f
#define GHM_C5  0.0f
#define GHM_C6 -0.40546511f
#define GHM_C7 -0.84729786f
#define GHM_C8 -1.38629436f
#define GHM_C9 -2.19722458f
#define LOG2E 1.44269504f

__global__ __launch_bounds__(NTHREADS, 8) void ghm_pass1(
    const float* __restrict__ pred, const int* __restrict__ target,
    float* __restrict__ g_T,            // [BINS] cumulative bce sums (log2 dom)
    unsigned int* __restrict__ g_C,     // [BINS] cumulative counts (1..9 used)
    int n4, int n)
{
    float T[BINS];
    unsigned int cnt[BINS];             // cnt[0] unused (== N, known)
#pragma unroll
    for (int b = 0; b < BINS; ++b) { T[b] = 0.f; cnt[b] = 0u; }

    const float4* __restrict__ p4 = reinterpret_cast<const float4*>(pred);
    const int4*   __restrict__ t4 = reinterpret_cast<const int4*>(target);

    const int tid    = threadIdx.x;
    const int gtid   = blockIdx.x * NTHREADS + tid;
    const int stride = gridDim.x * NTHREADS;   // in float4 units
    const int step   = 2 * stride;

#define GHM_BODY(xv, tv)                                                     \
    {                                                                        \
        const float xs_[4] = {(xv).x, (xv).y, (xv).z, (xv).w};               \
        const int   ts_[4] = {(tv).x, (tv).y, (tv).z, (tv).w};               \
        _Pragma("unroll")                                                    \
        for (int j = 0; j < 4; ++j) {                                        \
            const float x = xs_[j];                                          \
            const float y = (ts_[j] != 0) ? x : -x;                          \
            const float E = __builtin_amdgcn_exp2f(-y * LOG2E);              \
            const float bce2 = __builtin_amdgcn_logf(1.0f + E);              \
            T[0] += bce2;                                                    \
            { const bool p = (y <= GHM_C1); T[1]+=p?bce2:0.f; cnt[1]+=p; }   \
            { const bool p = (y <= GHM_C2); T[2]+=p?bce2:0.f; cnt[2]+=p; }   \
            { const bool p = (y <= GHM_C3); T[3]+=p?bce2:0.f; cnt[3]+=p; }   \
            { const bool p = (y <= GHM_C4); T[4]+=p?bce2:0.f; cnt[4]+=p; }   \
            { const bool p = (y <= GHM_C5); T[5]+=p?bce2:0.f; cnt[5]+=p; }   \
            { const bool p = (y <= GHM_C6); T[6]+=p?bce2:0.f; cnt[6]+=p; }   \
            { const bool p = (y <= GHM_C7); T[7]+=p?bce2:0.f; cnt[7]+=p; }   \
            { const bool p = (y <= GHM_C8); T[8]+=p?bce2:0.f; cnt[8]+=p; }   \
            { const bool p = (y <= GHM_C9); T[9]+=p?bce2:0.f; cnt[9]+=p; }   \
        }                                                                    \
    }

    // Pipelined main loop: R full rounds of (idx, idx+stride), prefetch next.
    const int R = (step > 0) ? (n4 / step) : 0;   // for N=2^25, grid 2048: R=8
    if (R > 0) {
        int idx = gtid;
        float4 xa0 = p4[idx];
        int4   ta0 = t4[idx];
        float4 xa1 = p4[idx + stride];
        int4   ta1 = t4[idx + stride];
        for (int r = 1; r < R; ++r) {
            const int nidx = gtid + r * step;
            const float4 xb0 = p4[nidx];
            const int4   tb0 = t4[nidx];
            const float4 xb1 = p4[nidx + stride];
            const int4   tb1 = t4[nidx + stride];
            GHM_BODY(xa0, ta0);
            GHM_BODY(xa1, ta1);
            xa0 = xb0; ta0 = tb0; xa1 = xb1; ta1 = tb1;
        }
        GHM_BODY(xa0, ta0);
        GHM_BODY(xa1, ta1);
    }
    // Cleanup: remaining float4s (none when n4 % step == 0).
    for (int i = gtid + R * step; i < n4; i += stride) {
        const float4 xv = p4[i];
        const int4   tv = t4[i];
        GHM_BODY(xv, tv);
    }
    // Scalar tail (n % 4; empty for N=2^25).
    if (gtid == 0) {
        for (int i = n4 * 4; i < n; ++i) {
            const float x = pred[i];
            const float y = (target[i] != 0) ? x : -x;
            const float E = __builtin_amdgcn_exp2f(-y * LOG2E);
            const float bce2 = __builtin_amdgcn_logf(1.0f + E);
            T[0] += bce2;
            { const bool p = (y <= GHM_C1); T[1]+=p?bce2:0.f; cnt[1]+=p; }
            { const bool p = (y <= GHM_C2); T[2]+=p?bce2:0.f; cnt[2]+=p; }
            { const bool p = (y <= GHM_C3); T[3]+=p?bce2:0.f; cnt[3]+=p; }
            { const bool p = (y <= GHM_C4); T[4]+=p?bce2:0.f; cnt[4]+=p; }
            { const bool p = (y <= GHM_C5); T[5]+=p?bce2:0.f; cnt[5]+=p; }
            { const bool p = (y <= GHM_C6); T[6]+=p?bce2:0.f; cnt[6]+=p; }
            { const bool p = (y <= GHM_C7); T[7]+=p?bce2:0.f; cnt[7]+=p; }
            { const bool p = (y <= GHM_C8); T[8]+=p?bce2:0.f; cnt[8]+=p; }
            { const bool p = (y <= GHM_C9); T[9]+=p?bce2:0.f; cnt[9]+=p; }
        }
    }
#undef GHM_BODY

    // wave reduce -> block combine in LDS -> one global atomic per bin
    __shared__ float        r_T[BINS];
    __shared__ unsigned int r_C[BINS];
    if (tid < BINS) { r_T[tid] = 0.f; r_C[tid] = 0u; }
    __syncthreads();

    const int lane = tid & 63;
#pragma unroll
    for (int b = 0; b < BINS; ++b) {
        const float        v = wave_reduce_add(T[b]);
        const unsigned int c = (b > 0) ? wave_reduce_addu(cnt[b]) : 0u;
        if (lane == 0) {
            atomicAdd(&r_T[b], v);
            if (b > 0) atomicAdd(&r_C[b], c);
        }
    }
    __syncthreads();

    if (tid < BINS) {
        atomicAdd(&g_T[tid], r_T[tid]);
        atomicAdd(&g_C[tid], r_C[tid]);
    }
}

__global__ void ghm_finalize(const float* __restrict__ g_T,
                             const unsigned int* __restrict__ g_C,
                             const float* __restrict__ acc_sum,
                             float* __restrict__ out, float tot, unsigned int ntot)
{
    if (threadIdx.x == 0 && blockIdx.x == 0) {
        const float LN2 = 0.69314718056f;
        float S[BINS];
        float cntf[BINS];
#pragma unroll
        for (int b = 0; b < BINS; ++b) {
            const float        Tc = g_T[b];
            const float        Tn = (b + 1 < BINS) ? g_T[b + 1] : 0.f;
            const unsigned int Cc = (b == 0) ? ntot : g_C[b];
            const unsigned int Cn = (b + 1 < BINS) ? g_C[b + 1] : 0u;
            S[b]    = (Tc - Tn) * LN2;
            cntf[b] = (float)(Cc - Cn);
        }
        float binw[BINS];
        int nne = 0;
#pragma unroll
        for (int b = 0; b < BINS; ++b) {
            const bool ne = (cntf[b] > 0.0f);
            const float accn = ne ? (0.9f * acc_sum[b] + 0.1f * cntf[b]) : acc_sum[b];
            binw[b] = ne ? (tot / accn) : 0.0f;
            nne += ne ? 1 : 0;
        }
        const float scale = (nne > 0) ? (1.0f / (float)nne) : 1.0f;
        float res = 0.0f;
#pragma unroll
        for (int b = 0; b < BINS; ++b) res += (binw[b] * scale) * S[b];
        out[0] = res / tot;
    }
}

extern "C" void kernel_launch(void* const* d_in, const int* in_sizes, int n_in,
                              void* d_out, int out_size, void* d_ws, size_t ws_size,
                              hipStream_t stream) {
    const float* pred    = (const float*)d_in[0];
    const int*   target  = (const int*)d_in[1];
    const float* acc_sum = (const float*)d_in[2];
    float*       out     = (float*)d_out;

    const int n  = in_sizes[0];
    const int n4 = n / 4;

    float*        g_T = (float*)d_ws;
    unsigned int* g_C = (unsigned int*)((float*)d_ws + BINS);

    // Zero accumulators every call (ws poisoned once, not re-poisoned).
    hipMemsetAsync(d_ws, 0, 2 * BINS * sizeof(float), stream);

    ghm_pass1<<<2048, NTHREADS, 0, stream>>>(pred, target, g_T, g_C, n4, n);

    const float tot = (float)(n > 1 ? n : 1);
    ghm_finalize<<<1, 64, 0, stream>>>(g_T, g_C, acc_sum, out, tot, (unsigned int)n);
}